// Round 8
// baseline (169.209 us; speedup 1.0000x reference)
//
#include <hip/hip_runtime.h>
#include <hip/hip_bf16.h>

// ---------------------------------------------------------------------------
// Naive3DConvEncoder: scatter -> conv1(1->16, LDS-staged) -> conv2(16->32 MFMA)
//                      -> conv3(32->64 MFMA) -> FC (partials + reduce).
// B=32, N=16384, G=64.
// ws layout:
//   grid_u8 : 0          (8,388,608 B)   [dead after conv1]
//   w2b     : 65,536     (28,672 B bf16 [28 sh][32 oc][16 c], aliases grid)
//   w3b     : 131,072    (110,592 B bf16 [27 sh][64 oc][32 c], aliases grid)
//   c1b     : 8,388,608  (33,554,432 B bf16 channels-last [b][z][y][x][c16])
//   c2b     : 75,497,472 (8,388,608 B bf16 channels-last [b][z][y][x][c32])
//   feat    : 92,274,688 (4,194,304 B fp32 [b][oc][z][y][x])
//   part    : 96,468,992 (2,097,152 B fp32 [128 fc][32 b][128 l])
// ---------------------------------------------------------------------------

typedef __attribute__((ext_vector_type(8))) short bf16x8;
typedef __attribute__((ext_vector_type(4))) float f32x4;

__device__ inline unsigned short f2bf(float f) {
    __hip_bfloat16 h = __float2bfloat16(f);
    return *reinterpret_cast<unsigned short*>(&h);
}

__global__ void k_scatter(const float* __restrict__ coords,
                          unsigned char* __restrict__ grid) {
    int i = blockIdx.x * 256 + threadIdx.x;          // 524288 threads
    float cx = coords[3 * i + 0];
    float cy = coords[3 * i + 1];
    float cz = coords[3 * i + 2];
    int ix = (int)((cx + 1.0f) * 0.5f * 63.0f);      // trunc like astype(int32)
    int iy = (int)((cy + 1.0f) * 0.5f * 63.0f);
    int iz = (int)((cz + 1.0f) * 0.5f * 63.0f);
    ix = min(max(ix, 0), 63);
    iy = min(max(iy, 0), 63);
    iz = min(max(iz, 0), 63);
    int b = i >> 14;
    grid[((b * 64 + iz) * 64 + iy) * 64 + ix] = 1;
}

// conv1 (LDS-staged): block = (b, zb, yb, xb) -> outputs (4z, 8y, 8x).
// Halo 9x17x17 u8 -> LDS floats, x-parity-split, row stride 20 words
// (per-wave banks = (8y+x)%32 -> max 2-way, free). No inner bounds checks.
__global__ __launch_bounds__(256) void k_conv1(
        const unsigned char* __restrict__ grid,
        const float* __restrict__ w1,
        const float* __restrict__ b1,
        unsigned short* __restrict__ c1b) {
    __shared__ float hal[9 * 17 * 20];               // 12,240 B
    const int t = threadIdx.x;
    const int blk = blockIdx.x;                      // 4096 blocks
    const int b = blk >> 7;
    const int zb = (blk >> 4) & 7;
    const int yb = (blk >> 2) & 3;
    const int xb = blk & 3;
    const int iz0 = 8 * zb - 1, iy0 = 16 * yb - 1, ix0 = 16 * xb - 1;

    const unsigned char* g = grid + b * 262144;
    for (int i = t; i < 2601; i += 256) {
        int hz = i / 289, rm = i - hz * 289;
        int hy = rm / 17, hx = rm - hy * 17;
        int iz = iz0 + hz, iy = iy0 + hy, ix = ix0 + hx;
        bool ok = (iz >= 0) & (iy >= 0) & (ix >= 0); // upper edges can't overflow
        float v = ok ? (float)g[(iz * 64 + iy) * 64 + ix] : 0.0f;
        int ux = (hx & 1) ? 10 + (hx >> 1) : (hx >> 1);
        hal[(hz * 17 + hy) * 20 + ux] = v;
    }
    __syncthreads();

    const int x = t & 7, y = (t >> 3) & 7, tz = t >> 6;
    const int base = (2 * tz * 17) * 20 + (2 * y) * 20 + x;
    float in27[27];
#pragma unroll
    for (int kz = 0; kz < 3; ++kz)
#pragma unroll
        for (int ky = 0; ky < 3; ++ky)
#pragma unroll
            for (int kx = 0; kx < 3; ++kx) {
                int uxo = (kx == 1) ? 10 : ((kx == 2) ? 1 : 0);
                in27[kz * 9 + ky * 3 + kx] =
                    hal[base + (kz * 17 + ky) * 20 + uxo];
            }
    float r[16];
#pragma unroll
    for (int oc = 0; oc < 16; ++oc) {
        float acc = b1[oc];
#pragma unroll
        for (int k = 0; k < 27; ++k) acc = fmaf(w1[oc * 27 + k], in27[k], acc);
        r[oc] = fmaxf(acc, 0.0f);
    }
    unsigned int dw[8];
#pragma unroll
    for (int j = 0; j < 8; ++j)
        dw[j] = (unsigned int)f2bf(r[2 * j]) | ((unsigned int)f2bf(r[2 * j + 1]) << 16);
    int oz = 4 * zb + tz, oy = 8 * yb + y, ox = 8 * xb + x;
    size_t idx = ((size_t)(b * 32 + oz) * 32 + oy) * 32 + ox;
    char* base_o = (char*)c1b + idx * 32;
    *(int4*)base_o        = int4{(int)dw[0], (int)dw[1], (int)dw[2], (int)dw[3]};
    *(int4*)(base_o + 16) = int4{(int)dw[4], (int)dw[5], (int)dw[6], (int)dw[7]};
}

// Weight prep: w2b bf16 [sh 28][oc 32][c 16] (sh 27 zero-padded);
//              w3b bf16 [sh 27][oc 64][c 32].
__global__ void k_wtrans(const float* __restrict__ w2, unsigned short* __restrict__ w2b,
                         const float* __restrict__ w3, unsigned short* __restrict__ w3b) {
    int i = blockIdx.x * 256 + threadIdx.x;          // 272 blocks = 69632 threads
    if (i < 14336) {
        int sh = i >> 9, oc = (i >> 4) & 31, c = i & 15;
        float v = (sh < 27) ? w2[oc * 432 + c * 27 + sh] : 0.0f;
        w2b[i] = f2bf(v);
    } else {
        int j = i - 14336;
        if (j < 55296) {
            int sh = j >> 11, oc = (j >> 5) & 63, c = j & 31;
            w3b[j] = f2bf(w3[oc * 864 + c * 27 + sh]);
        }
    }
}

// ---------------------------------------------------------------------------
// conv2 as implicit GEMM on MFMA 16x16x32 bf16 (parity-split-y slab).
// ---------------------------------------------------------------------------
__device__ constexpr int abase(int sh) {
    return (sh / 9) * 35376 + (((sh % 9) / 3) & 1) * 18224 +
           (((sh % 9) / 3) >> 1) * 1072 + (sh % 3) * 32;
}

__global__ __launch_bounds__(512) void k_conv2_mfma(
        const unsigned short* __restrict__ c1b,
        const unsigned short* __restrict__ w2b,
        const float* __restrict__ b2,
        unsigned short* __restrict__ c2b) {
    __shared__ __align__(16) char smem[106128];
    const int t = threadIdx.x;
    const int b = blockIdx.x >> 4;
    const int zo = blockIdx.x & 15;
    const int lane = t & 63;
    const int wid = t >> 6;                          // 8 waves

    {
        const int4 z4 = {0, 0, 0, 0};
        if (t < 198) {                               // even row 0 (iy_in = -1)
            int p = t / 66, r = t % 66;
            int col = r >> 1, h = r & 1;
            *(int4*)(smem + p * 35376 + col * 32 + h * 16) = z4;
        }
        if (t >= 256 && t < 454) {                   // col 0 (ix_in = -1), all rows
            int i = t - 256;
            int p = i / 66, r = i % 66;
            int row33 = r >> 1, h = r & 1;
            int off = (row33 < 17) ? row33 * 1072 : 18224 + (row33 - 17) * 1072;
            *(int4*)(smem + p * 35376 + off + h * 16) = z4;
        }
    }

    const char* src = (const char*)c1b + (size_t)b * (32768 * 32);
#pragma unroll
    for (int i = 0; i < 6; ++i) {
        const int p = i >> 1;
        int pos = ((i & 1) << 9) + t;                // 0..1023
        int iy = pos >> 5, ix = pos & 31;
        int iz = 2 * zo + p - 1;
        int4 v0 = {0, 0, 0, 0}, v1 = {0, 0, 0, 0};
        if (iz >= 0) {
            const char* gp = src + ((size_t)(iz * 1024 + pos)) * 32;
            v0 = *(const int4*)gp;
            v1 = *(const int4*)(gp + 16);
        }
        int iy_st = iy + 1;
        char* d = smem + p * 35376 + ((iy_st & 1) ? 18224 : 0) + (iy_st >> 1) * 1072 +
                  (ix + 1) * 32;
        *(int4*)d = v0;
        *(int4*)(d + 16) = v1;
    }
    __syncthreads();

    const int y = lane & 15;
    const int g = lane >> 4;
    const int h = g & 1;
    const int s = g >> 1;
    const int laneA = y * 1072 + h * 16;
    const int laneB = (lane & 15) * 32 + h * 16 + s * 1024;
    const int x0 = wid * 2;
    const char* wbase = (const char*)w2b;

    f32x4 acc00 = {0, 0, 0, 0}, acc01 = {0, 0, 0, 0};
    f32x4 acc10 = {0, 0, 0, 0}, acc11 = {0, 0, 0, 0};

#pragma unroll
    for (int sp = 0; sp < 14; ++sp) {
        const int sh0 = 2 * sp;
        const int sh1 = (2 * sp + 1 < 27) ? 2 * sp + 1 : 26;
        const int a0 = abase(sh0);
        const int d01 = abase(sh1) - a0;
        const int addrA = laneA + a0 + (s ? d01 : 0) + x0 * 64;
        bf16x8 A0 = *(const bf16x8*)(smem + addrA);
        bf16x8 A1 = *(const bf16x8*)(smem + addrA + 64);
        const char* wb = wbase + sp * 2048 + laneB;
        bf16x8 B0 = *(const bf16x8*)wb;
        bf16x8 B1 = *(const bf16x8*)(wb + 512);
        acc00 = __builtin_amdgcn_mfma_f32_16x16x32_bf16(A0, B0, acc00, 0, 0, 0);
        acc01 = __builtin_amdgcn_mfma_f32_16x16x32_bf16(A0, B1, acc01, 0, 0, 0);
        acc10 = __builtin_amdgcn_mfma_f32_16x16x32_bf16(A1, B0, acc10, 0, 0, 0);
        acc11 = __builtin_amdgcn_mfma_f32_16x16x32_bf16(A1, B1, acc11, 0, 0, 0);
    }

    __syncthreads();
    float* sOut = (float*)smem;                      // [32 oc][257]
    {
        int ocl = lane & 15;
        int yb = (lane >> 4) * 4;
#pragma unroll
        for (int r = 0; r < 4; ++r) {
            sOut[ocl * 257        + (yb + r) * 16 + x0    ] = acc00[r];
            sOut[(ocl + 16) * 257 + (yb + r) * 16 + x0    ] = acc01[r];
            sOut[ocl * 257        + (yb + r) * 16 + x0 + 1] = acc10[r];
            sOut[(ocl + 16) * 257 + (yb + r) * 16 + x0 + 1] = acc11[r];
        }
    }
    __syncthreads();
    {
        int m = t >> 1, half = t & 1;
        unsigned int dw[8];
#pragma unroll
        for (int j = 0; j < 8; ++j) {
            int oc0 = half * 16 + 2 * j;
            float v0 = fmaxf(sOut[oc0 * 257 + m] + b2[oc0], 0.0f);
            float v1 = fmaxf(sOut[(oc0 + 1) * 257 + m] + b2[oc0 + 1], 0.0f);
            dw[j] = (unsigned int)f2bf(v0) | ((unsigned int)f2bf(v1) << 16);
        }
        char* dst = (char*)c2b + ((size_t)b * 4096 + zo * 256 + m) * 64 + half * 32;
        *(int4*)dst        = int4{(int)dw[0], (int)dw[1], (int)dw[2], (int)dw[3]};
        *(int4*)(dst + 16) = int4{(int)dw[4], (int)dw[5], (int)dw[6], (int)dw[7]};
    }
}

// ---------------------------------------------------------------------------
// conv3 as implicit GEMM on MFMA 16x16x32 bf16 (x-parity-split voxels).
// ---------------------------------------------------------------------------
__global__ __launch_bounds__(512) void k_conv3_mfma(
        const unsigned short* __restrict__ c2b,
        const unsigned short* __restrict__ w3b,
        const float* __restrict__ b3,
        float* __restrict__ feat) {
    __shared__ __align__(16) char smem[55488];
    const int t = threadIdx.x;
    const int b = blockIdx.x >> 3;
    const int zo = blockIdx.x & 7;
    const int lane = t & 63;
    const int wid = t >> 6;                          // 8 waves

    if (t < 396) {
        int p3 = t / 132, j = t % 132;
        int v = j >> 2, g = j & 3;
        int iy_st = (v < 17) ? 0 : (v - 16);
        int ix_st = (v < 17) ? v : 0;
        int ux = (ix_st & 1) ? 9 + (ix_st >> 1) : (ix_st >> 1);
        int u = (p3 * 17 + iy_st) * 17 + ux;
        *(int4*)(smem + u * 64 + g * 16) = int4{0, 0, 0, 0};
    }

    const char* src = (const char*)c2b + (size_t)b * 262144;
#pragma unroll
    for (int r = 0; r < 6; ++r) {
        int i = r * 512 + t;
        int g = i & 3, vox = i >> 2;
        int kz = vox >> 8, pos = vox & 255;
        int iy = pos >> 4, ix = pos & 15;
        int iz = 2 * zo + kz - 1;
        int4 v = {0, 0, 0, 0};
        if (iz >= 0)
            v = *(const int4*)(src + ((size_t)(iz * 256 + pos)) * 64 + g * 16);
        int ix_st = ix + 1;
        int ux = (ix_st & 1) ? 9 + (ix_st >> 1) : (ix_st >> 1);
        int u = (kz * 17 + iy + 1) * 17 + ux;
        *(int4*)(smem + u * 64 + g * 16) = v;
    }
    __syncthreads();

    const int mt = wid >> 1;
    const int ntp = wid & 1;
    const int m = mt * 16 + (lane & 15);
    const int y = m >> 3, x = m & 7;
    const int g = lane >> 4;
    const int laneA = (34 * y + x) * 64 + g * 16;
    const char* wb_base = (const char*)w3b + (ntp * 32 + (lane & 15)) * 64 + g * 16;

    f32x4 acc0 = {0, 0, 0, 0}, acc1 = {0, 0, 0, 0};

#pragma unroll
    for (int sh = 0; sh < 27; ++sh) {
        const int kz = sh / 9, ky = (sh % 9) / 3, kx = sh % 3;
        const int uxc = (kx == 0) ? 0 : ((kx == 1) ? 9 : 1);
        const int aoff = (289 * kz + 17 * ky + uxc) * 64;
        bf16x8 A = *(const bf16x8*)(smem + laneA + aoff);
        const char* wb = wb_base + sh * 4096;
        bf16x8 B0 = *(const bf16x8*)wb;
        bf16x8 B1 = *(const bf16x8*)(wb + 1024);
        acc0 = __builtin_amdgcn_mfma_f32_16x16x32_bf16(A, B0, acc0, 0, 0, 0);
        acc1 = __builtin_amdgcn_mfma_f32_16x16x32_bf16(A, B1, acc1, 0, 0, 0);
    }

    __syncthreads();
    float* sOut = (float*)smem;                      // [64 oc][65]
    {
        int ocl = lane & 15;
        int mb = mt * 16 + (lane >> 4) * 4;
#pragma unroll
        for (int r = 0; r < 4; ++r) {
            sOut[(ntp * 32 + ocl) * 65 + mb + r]      = acc0[r];
            sOut[(ntp * 32 + 16 + ocl) * 65 + mb + r] = acc1[r];
        }
    }
    __syncthreads();
    {
        int oc = t >> 3, q = t & 7;
        float bb = b3[oc];
        float* dst = feat + (size_t)b * 32768 + oc * 512 + zo * 64 + q * 8;
#pragma unroll
        for (int k = 0; k < 8; ++k) {
            float v = sOut[oc * 65 + q * 8 + k] + bb;
            dst[k] = fmaxf(v, 0.0f);
        }
    }
}

// FC stage 1: partials, NO atomics. Block (fchunk, lg) owns l-range
// [lg*32, lg*32+32) -> part[fc][b][l] written exactly once.
__global__ void k_fc_partial(const float* __restrict__ feat,
                             const float* __restrict__ fc_w,
                             float* __restrict__ part) {
    __shared__ float lds[256 * 36];
    int fchunk = blockIdx.x & 127;
    int lg = blockIdx.x >> 7;
    int t = threadIdx.x;
    int f0 = fchunk * 256;
    for (int b = 0; b < 32; ++b)
        lds[t * 36 + b] = feat[b * 32768 + f0 + t];
    __syncthreads();

    int l = lg * 32 + (t >> 3);
    int bq = t & 7;
    const float* wrow = fc_w + l * 32768 + f0;
    float a0 = 0.f, a1 = 0.f, a2 = 0.f, a3 = 0.f;
    for (int f = 0; f < 256; ++f) {
        float wv = wrow[f];
        const float* p = &lds[f * 36 + bq * 4];
        a0 = fmaf(p[0], wv, a0);
        a1 = fmaf(p[1], wv, a1);
        a2 = fmaf(p[2], wv, a2);
        a3 = fmaf(p[3], wv, a3);
    }
    int b0 = bq * 4;
    float* pd = part + (size_t)fchunk * 4096 + l;
    pd[(b0 + 0) * 128] = a0;
    pd[(b0 + 1) * 128] = a1;
    pd[(b0 + 2) * 128] = a2;
    pd[(b0 + 3) * 128] = a3;
}

// FC stage 2: out[b][l] = sum_fc part[fc][b][l] + fc_b[l]. Coalesced reads.
__global__ void k_fc_reduce(const float* __restrict__ part,
                            const float* __restrict__ fc_b,
                            float* __restrict__ out) {
    int idx = blockIdx.x * 256 + threadIdx.x;        // 4096
    int l = idx & 127;
    float s = fc_b[l];
#pragma unroll 8
    for (int fc = 0; fc < 128; ++fc)
        s += part[fc * 4096 + idx];
    out[idx] = s;
}

extern "C" void kernel_launch(void* const* d_in, const int* in_sizes, int n_in,
                              void* d_out, int out_size, void* d_ws, size_t ws_size,
                              hipStream_t stream) {
    const float* coords = (const float*)d_in[0];
    const float* w1 = (const float*)d_in[1];
    const float* b1 = (const float*)d_in[2];
    const float* w2 = (const float*)d_in[3];
    const float* b2 = (const float*)d_in[4];
    const float* w3 = (const float*)d_in[5];
    const float* b3 = (const float*)d_in[6];
    const float* fc_w = (const float*)d_in[7];
    const float* fc_b = (const float*)d_in[8];

    unsigned char* grid_u8 = (unsigned char*)d_ws;
    unsigned short* w2b = (unsigned short*)((char*)d_ws + 65536);   // aliases grid
    unsigned short* w3b = (unsigned short*)((char*)d_ws + 131072);  // aliases grid
    unsigned short* c1b = (unsigned short*)((char*)d_ws + 8388608);
    unsigned short* c2b = (unsigned short*)((char*)d_ws + 75497472);
    float* feat = (float*)((char*)d_ws + 92274688);
    float* part = (float*)((char*)d_ws + 96468992);
    float* out = (float*)d_out;

    hipMemsetAsync(grid_u8, 0, 8388608, stream);

    k_scatter<<<2048, 256, 0, stream>>>(coords, grid_u8);
    k_conv1<<<4096, 256, 0, stream>>>(grid_u8, w1, b1, c1b);
    k_wtrans<<<272, 256, 0, stream>>>(w2, w2b, w3, w3b);            // grid dead now
    k_conv2_mfma<<<512, 512, 0, stream>>>(c1b, w2b, b2, c2b);
    k_conv3_mfma<<<256, 512, 0, stream>>>(c2b, w3b, b3, feat);
    k_fc_partial<<<512, 256, 0, stream>>>(feat, fc_w, part);
    k_fc_reduce<<<16, 256, 0, stream>>>(part, fc_b, out);
}

// Round 9
// 163.558 us; speedup vs baseline: 1.0346x; 1.0346x over previous
//
#include <hip/hip_runtime.h>
#include <hip/hip_bf16.h>

// ---------------------------------------------------------------------------
// Naive3DConvEncoder: scatter+wtrans -> conv1 -> conv2(MFMA, x-split) ->
//                      conv3(MFMA) -> fc_partial -> fc_reduce.
// B=32, N=16384, G=64.
// ws layout:
//   grid_u8 : 0           (8,388,608 B)  [dead after conv1]
//   c1b     : 8,388,608   (33,554,432 B bf16 [b][z][y][x][c16])
//   c2b     : 75,497,472  (8,388,608 B bf16 [b][z][y][x][c32])
//   feat    : 92,274,688  (4,194,304 B fp32 [b][oc][z][y][x])
//   part    : 96,468,992  (2,097,152 B fp32 [128 fc][32 b][128 l])
//   w2b     : 98,566,144  (28,672 B bf16 [28 sh][32 oc][16 c])
//   w3b     : 98,697,216  (110,592 B bf16 [27 sh][64 oc][32 c])
// w2b/w3b no longer alias grid_u8 (wtrans now runs BEFORE conv1).
// ---------------------------------------------------------------------------

typedef __attribute__((ext_vector_type(8))) short bf16x8;
typedef __attribute__((ext_vector_type(4))) float f32x4;

__device__ inline unsigned short f2bf(float f) {
    __hip_bfloat16 h = __float2bfloat16(f);
    return *reinterpret_cast<unsigned short*>(&h);
}

// Fused: blocks 0..2047 scatter points; blocks 2048..2319 transpose weights.
__global__ void k_scatter_wtrans(const float* __restrict__ coords,
                                 unsigned char* __restrict__ grid,
                                 const float* __restrict__ w2,
                                 unsigned short* __restrict__ w2b,
                                 const float* __restrict__ w3,
                                 unsigned short* __restrict__ w3b) {
    int blk = blockIdx.x;
    if (blk < 2048) {
        int i = blk * 256 + threadIdx.x;             // 524288 threads
        float cx = coords[3 * i + 0];
        float cy = coords[3 * i + 1];
        float cz = coords[3 * i + 2];
        int ix = (int)((cx + 1.0f) * 0.5f * 63.0f);
        int iy = (int)((cy + 1.0f) * 0.5f * 63.0f);
        int iz = (int)((cz + 1.0f) * 0.5f * 63.0f);
        ix = min(max(ix, 0), 63);
        iy = min(max(iy, 0), 63);
        iz = min(max(iz, 0), 63);
        int b = i >> 14;
        grid[((b * 64 + iz) * 64 + iy) * 64 + ix] = 1;
    } else {
        int i = (blk - 2048) * 256 + threadIdx.x;    // 0..69631
        if (i < 14336) {
            int sh = i >> 9, oc = (i >> 4) & 31, c = i & 15;
            float v = (sh < 27) ? w2[oc * 432 + c * 27 + sh] : 0.0f;
            w2b[i] = f2bf(v);
        } else {
            int j = i - 14336;
            if (j < 55296) {
                int sh = j >> 11, oc = (j >> 5) & 63, c = j & 31;
                w3b[j] = f2bf(w3[oc * 864 + c * 27 + sh]);
            }
        }
    }
}

// conv1 (LDS-staged halo): block = (b, zb, yb, xb) -> outputs (4z, 8y, 8x).
__global__ __launch_bounds__(256) void k_conv1(
        const unsigned char* __restrict__ grid,
        const float* __restrict__ w1,
        const float* __restrict__ b1,
        unsigned short* __restrict__ c1b) {
    __shared__ float hal[9 * 17 * 20];               // 12,240 B
    const int t = threadIdx.x;
    const int blk = blockIdx.x;                      // 4096 blocks
    const int b = blk >> 7;
    const int zb = (blk >> 4) & 7;
    const int yb = (blk >> 2) & 3;
    const int xb = blk & 3;
    const int iz0 = 8 * zb - 1, iy0 = 16 * yb - 1, ix0 = 16 * xb - 1;

    const unsigned char* g = grid + b * 262144;
    for (int i = t; i < 2601; i += 256) {
        int hz = i / 289, rm = i - hz * 289;
        int hy = rm / 17, hx = rm - hy * 17;
        int iz = iz0 + hz, iy = iy0 + hy, ix = ix0 + hx;
        bool ok = (iz >= 0) & (iy >= 0) & (ix >= 0);
        float v = ok ? (float)g[(iz * 64 + iy) * 64 + ix] : 0.0f;
        int ux = (hx & 1) ? 10 + (hx >> 1) : (hx >> 1);
        hal[(hz * 17 + hy) * 20 + ux] = v;
    }
    __syncthreads();

    const int x = t & 7, y = (t >> 3) & 7, tz = t >> 6;
    const int base = (2 * tz * 17) * 20 + (2 * y) * 20 + x;
    float in27[27];
#pragma unroll
    for (int kz = 0; kz < 3; ++kz)
#pragma unroll
        for (int ky = 0; ky < 3; ++ky)
#pragma unroll
            for (int kx = 0; kx < 3; ++kx) {
                int uxo = (kx == 1) ? 10 : ((kx == 2) ? 1 : 0);
                in27[kz * 9 + ky * 3 + kx] =
                    hal[base + (kz * 17 + ky) * 20 + uxo];
            }
    float r[16];
#pragma unroll
    for (int oc = 0; oc < 16; ++oc) {
        float acc = b1[oc];
#pragma unroll
        for (int k = 0; k < 27; ++k) acc = fmaf(w1[oc * 27 + k], in27[k], acc);
        r[oc] = fmaxf(acc, 0.0f);
    }
    unsigned int dw[8];
#pragma unroll
    for (int j = 0; j < 8; ++j)
        dw[j] = (unsigned int)f2bf(r[2 * j]) | ((unsigned int)f2bf(r[2 * j + 1]) << 16);
    int oz = 4 * zb + tz, oy = 8 * yb + y, ox = 8 * xb + x;
    size_t idx = ((size_t)(b * 32 + oz) * 32 + oy) * 32 + ox;
    char* base_o = (char*)c1b + idx * 32;
    *(int4*)base_o        = int4{(int)dw[0], (int)dw[1], (int)dw[2], (int)dw[3]};
    *(int4*)(base_o + 16) = int4{(int)dw[4], (int)dw[5], (int)dw[6], (int)dw[7]};
}

// ---------------------------------------------------------------------------
// conv2 implicit GEMM, x-SPLIT for occupancy: block=(b,zo,xh), M=128 (16y x 8x),
// N=32 oc, K=432 as 14 shift-pairs. LDS slab: 3 planes, y-parity-split rows,
// 17 cols/row, row stride 560 B -> 55,440 B -> 2 blocks/CU at <=128 VGPR.
// Per wave: 1 x-col, 1 A ds_read + 2 B global (L2) + 2 MFMA per sp.
// ---------------------------------------------------------------------------
__device__ constexpr int abase2(int sh) {
    return (sh / 9) * 18480 + (((sh % 9) / 3) & 1) * 9520 +
           (((sh % 9) / 3) >> 1) * 560 + (sh % 3) * 32;
}

__global__ __launch_bounds__(512, 4) void k_conv2_mfma(
        const unsigned short* __restrict__ c1b,
        const unsigned short* __restrict__ w2b,
        const float* __restrict__ b2,
        unsigned short* __restrict__ c2b) {
    __shared__ __align__(16) char smem[55440];
    const int t = threadIdx.x;
    const int b = blockIdx.x >> 5;
    const int zo = (blockIdx.x >> 1) & 15;
    const int xh = blockIdx.x & 1;
    const int lane = t & 63;
    const int wid = t >> 6;                          // 8 waves -> x_l = wid

    // stage 3 planes x 33 rows x 17 cols (zero-filled at iz/iy/ix == -1)
    const char* src = (const char*)c1b + (size_t)b * (32768 * 32);
    for (int i = t; i < 1683; i += 512) {
        int kz = i / 561, rem = i - kz * 561;
        int iy_st = rem / 17, c = rem - iy_st * 17;
        int iz = 2 * zo + kz - 1;
        int iy = iy_st - 1;
        int ix = (xh << 4) + c - 1;
        int4 v0 = {0, 0, 0, 0}, v1 = {0, 0, 0, 0};
        if ((iz >= 0) & (iy >= 0) & (ix >= 0)) {
            const char* gp = src + ((size_t)((iz * 32 + iy) * 32 + ix)) * 32;
            v0 = *(const int4*)gp;
            v1 = *(const int4*)(gp + 16);
        }
        char* d = smem + kz * 18480 + (iy_st & 1) * 9520 + (iy_st >> 1) * 560 + c * 32;
        *(int4*)d = v0;
        *(int4*)(d + 16) = v1;
    }
    __syncthreads();

    const int y16 = lane & 15;
    const int g = lane >> 4;
    const int h = g & 1;
    const int s = g >> 1;
    const int laneA = y16 * 560 + h * 16;
    const int laneB = (lane & 15) * 32 + h * 16 + s * 1024;
    const int xl64 = wid * 64;
    const char* wbase = (const char*)w2b;

    f32x4 acc0 = {0, 0, 0, 0}, acc1 = {0, 0, 0, 0};

#pragma unroll
    for (int sp = 0; sp < 14; ++sp) {
        const int sh0 = 2 * sp;
        const int sh1 = (2 * sp + 1 < 27) ? 2 * sp + 1 : 26;  // pad pair (B=0 there)
        const int a0 = abase2(sh0);
        const int d01 = abase2(sh1) - a0;
        bf16x8 A = *(const bf16x8*)(smem + laneA + a0 + (s ? d01 : 0) + xl64);
        const char* wb = wbase + sp * 2048 + laneB;
        bf16x8 B0 = *(const bf16x8*)wb;
        bf16x8 B1 = *(const bf16x8*)(wb + 512);
        acc0 = __builtin_amdgcn_mfma_f32_16x16x32_bf16(A, B0, acc0, 0, 0, 0);
        acc1 = __builtin_amdgcn_mfma_f32_16x16x32_bf16(A, B1, acc1, 0, 0, 0);
    }

    // epilogue: transpose through LDS, pack bf16 channels-last c2b.
    __syncthreads();
    float* sOut = (float*)smem;                      // [32 oc][129]
    {
        int ocl = lane & 15;
        int yb = (lane >> 4) * 4;
#pragma unroll
        for (int r = 0; r < 4; ++r) {
            sOut[ocl * 129        + (yb + r) * 8 + wid] = acc0[r];
            sOut[(ocl + 16) * 129 + (yb + r) * 8 + wid] = acc1[r];
        }
    }
    __syncthreads();
    {
        int vox = t >> 2, q = t & 3;                 // vox = y*8 + xl
        unsigned int dw[4];
#pragma unroll
        for (int j = 0; j < 4; ++j) {
            int oc0 = 8 * q + 2 * j;
            float v0 = fmaxf(sOut[oc0 * 129 + vox] + b2[oc0], 0.0f);
            float v1 = fmaxf(sOut[(oc0 + 1) * 129 + vox] + b2[oc0 + 1], 0.0f);
            dw[j] = (unsigned int)f2bf(v0) | ((unsigned int)f2bf(v1) << 16);
        }
        char* dst = (char*)c2b +
                    ((size_t)b * 4096 + zo * 256 + (vox >> 3) * 16 + xh * 8 + (vox & 7)) * 64 +
                    q * 16;
        *(int4*)dst = int4{(int)dw[0], (int)dw[1], (int)dw[2], (int)dw[3]};
    }
}

// ---------------------------------------------------------------------------
// conv3 implicit GEMM (x-parity-split voxels), unchanged from r7/r8.
// ---------------------------------------------------------------------------
__global__ __launch_bounds__(512) void k_conv3_mfma(
        const unsigned short* __restrict__ c2b,
        const unsigned short* __restrict__ w3b,
        const float* __restrict__ b3,
        float* __restrict__ feat) {
    __shared__ __align__(16) char smem[55488];
    const int t = threadIdx.x;
    const int b = blockIdx.x >> 3;
    const int zo = blockIdx.x & 7;
    const int lane = t & 63;
    const int wid = t >> 6;

    if (t < 396) {
        int p3 = t / 132, j = t % 132;
        int v = j >> 2, g = j & 3;
        int iy_st = (v < 17) ? 0 : (v - 16);
        int ix_st = (v < 17) ? v : 0;
        int ux = (ix_st & 1) ? 9 + (ix_st >> 1) : (ix_st >> 1);
        int u = (p3 * 17 + iy_st) * 17 + ux;
        *(int4*)(smem + u * 64 + g * 16) = int4{0, 0, 0, 0};
    }

    const char* src = (const char*)c2b + (size_t)b * 262144;
#pragma unroll
    for (int r = 0; r < 6; ++r) {
        int i = r * 512 + t;
        int g = i & 3, vox = i >> 2;
        int kz = vox >> 8, pos = vox & 255;
        int iy = pos >> 4, ix = pos & 15;
        int iz = 2 * zo + kz - 1;
        int4 v = {0, 0, 0, 0};
        if (iz >= 0)
            v = *(const int4*)(src + ((size_t)(iz * 256 + pos)) * 64 + g * 16);
        int ix_st = ix + 1;
        int ux = (ix_st & 1) ? 9 + (ix_st >> 1) : (ix_st >> 1);
        int u = (kz * 17 + iy + 1) * 17 + ux;
        *(int4*)(smem + u * 64 + g * 16) = v;
    }
    __syncthreads();

    const int mt = wid >> 1;
    const int ntp = wid & 1;
    const int m = mt * 16 + (lane & 15);
    const int y = m >> 3, x = m & 7;
    const int g = lane >> 4;
    const int laneA = (34 * y + x) * 64 + g * 16;
    const char* wb_base = (const char*)w3b + (ntp * 32 + (lane & 15)) * 64 + g * 16;

    f32x4 acc0 = {0, 0, 0, 0}, acc1 = {0, 0, 0, 0};

#pragma unroll
    for (int sh = 0; sh < 27; ++sh) {
        const int kz = sh / 9, ky = (sh % 9) / 3, kx = sh % 3;
        const int uxc = (kx == 0) ? 0 : ((kx == 1) ? 9 : 1);
        const int aoff = (289 * kz + 17 * ky + uxc) * 64;
        bf16x8 A = *(const bf16x8*)(smem + laneA + aoff);
        const char* wb = wb_base + sh * 4096;
        bf16x8 B0 = *(const bf16x8*)wb;
        bf16x8 B1 = *(const bf16x8*)(wb + 1024);
        acc0 = __builtin_amdgcn_mfma_f32_16x16x32_bf16(A, B0, acc0, 0, 0, 0);
        acc1 = __builtin_amdgcn_mfma_f32_16x16x32_bf16(A, B1, acc1, 0, 0, 0);
    }

    __syncthreads();
    float* sOut = (float*)smem;                      // [64 oc][65]
    {
        int ocl = lane & 15;
        int mb = mt * 16 + (lane >> 4) * 4;
#pragma unroll
        for (int r = 0; r < 4; ++r) {
            sOut[(ntp * 32 + ocl) * 65 + mb + r]      = acc0[r];
            sOut[(ntp * 32 + 16 + ocl) * 65 + mb + r] = acc1[r];
        }
    }
    __syncthreads();
    {
        int oc = t >> 3, q = t & 7;
        float bb = b3[oc];
        float* dst = feat + (size_t)b * 32768 + oc * 512 + zo * 64 + q * 8;
#pragma unroll
        for (int k = 0; k < 8; ++k) {
            float v = sOut[oc * 65 + q * 8 + k] + bb;
            dst[k] = fmaxf(v, 0.0f);
        }
    }
}

// FC stage 1: partials, no atomics; float4-vectorized weight stream.
__global__ void k_fc_partial(const float* __restrict__ feat,
                             const float* __restrict__ fc_w,
                             float* __restrict__ part) {
    __shared__ float lds[256 * 36];
    int fchunk = blockIdx.x & 127;
    int lg = blockIdx.x >> 7;
    int t = threadIdx.x;
    int f0 = fchunk * 256;
    for (int b = 0; b < 32; ++b)
        lds[t * 36 + b] = feat[b * 32768 + f0 + t];
    __syncthreads();

    int l = lg * 32 + (t >> 3);
    int bq = t & 7;
    const float* wrow = fc_w + l * 32768 + f0;
    float a0 = 0.f, a1 = 0.f, a2 = 0.f, a3 = 0.f;
    for (int f4 = 0; f4 < 64; ++f4) {
        float4 w4 = *(const float4*)(wrow + f4 * 4);
        const float* p = &lds[(f4 * 4) * 36 + bq * 4];
        a0 = fmaf(p[0], w4.x, a0); a1 = fmaf(p[1], w4.x, a1);
        a2 = fmaf(p[2], w4.x, a2); a3 = fmaf(p[3], w4.x, a3);
        p += 36;
        a0 = fmaf(p[0], w4.y, a0); a1 = fmaf(p[1], w4.y, a1);
        a2 = fmaf(p[2], w4.y, a2); a3 = fmaf(p[3], w4.y, a3);
        p += 36;
        a0 = fmaf(p[0], w4.z, a0); a1 = fmaf(p[1], w4.z, a1);
        a2 = fmaf(p[2], w4.z, a2); a3 = fmaf(p[3], w4.z, a3);
        p += 36;
        a0 = fmaf(p[0], w4.w, a0); a1 = fmaf(p[1], w4.w, a1);
        a2 = fmaf(p[2], w4.w, a2); a3 = fmaf(p[3], w4.w, a3);
    }
    int b0 = bq * 4;
    float* pd = part + (size_t)fchunk * 4096 + l;
    pd[(b0 + 0) * 128] = a0;
    pd[(b0 + 1) * 128] = a1;
    pd[(b0 + 2) * 128] = a2;
    pd[(b0 + 3) * 128] = a3;
}

// FC stage 2: out[b][l] = sum_fc part[fc][b][l] + fc_b[l].
__global__ void k_fc_reduce(const float* __restrict__ part,
                            const float* __restrict__ fc_b,
                            float* __restrict__ out) {
    int idx = blockIdx.x * 256 + threadIdx.x;        // 4096
    int l = idx & 127;
    float s = fc_b[l];
#pragma unroll 8
    for (int fc = 0; fc < 128; ++fc)
        s += part[fc * 4096 + idx];
    out[idx] = s;
}

extern "C" void kernel_launch(void* const* d_in, const int* in_sizes, int n_in,
                              void* d_out, int out_size, void* d_ws, size_t ws_size,
                              hipStream_t stream) {
    const float* coords = (const float*)d_in[0];
    const float* w1 = (const float*)d_in[1];
    const float* b1 = (const float*)d_in[2];
    const float* w2 = (const float*)d_in[3];
    const float* b2 = (const float*)d_in[4];
    const float* w3 = (const float*)d_in[5];
    const float* b3 = (const float*)d_in[6];
    const float* fc_w = (const float*)d_in[7];
    const float* fc_b = (const float*)d_in[8];

    unsigned char* grid_u8 = (unsigned char*)d_ws;
    unsigned short* c1b = (unsigned short*)((char*)d_ws + 8388608);
    unsigned short* c2b = (unsigned short*)((char*)d_ws + 75497472);
    float* feat = (float*)((char*)d_ws + 92274688);
    float* part = (float*)((char*)d_ws + 96468992);
    unsigned short* w2b = (unsigned short*)((char*)d_ws + 98566144);
    unsigned short* w3b = (unsigned short*)((char*)d_ws + 98697216);
    float* out = (float*)d_out;

    hipMemsetAsync(grid_u8, 0, 8388608, stream);

    k_scatter_wtrans<<<2320, 256, 0, stream>>>(coords, grid_u8, w2, w2b, w3, w3b);
    k_conv1<<<4096, 256, 0, stream>>>(grid_u8, w1, b1, c1b);
    k_conv2_mfma<<<1024, 512, 0, stream>>>(c1b, w2b, b2, c2b);
    k_conv3_mfma<<<256, 512, 0, stream>>>(c2b, w3b, b3, feat);
    k_fc_partial<<<512, 256, 0, stream>>>(feat, fc_w, part);
    k_fc_reduce<<<16, 256, 0, stream>>>(part, fc_b, out);
}

// Round 10
// 159.779 us; speedup vs baseline: 1.0590x; 1.0236x over previous
//
#include <hip/hip_runtime.h>
#include <hip/hip_bf16.h>

// ---------------------------------------------------------------------------
// Naive3DConvEncoder: scatter+wtrans+fcw -> conv1 -> conv2(MFMA) -> conv3(MFMA)
//                      -> fc(MFMA, atomic epilogue).  B=32, N=16384, G=64.
// ws layout:
//   grid_u8 : 0           (8,388,608 B)  [dead after conv1]
//   c1b     : 8,388,608   (33,554,432 B bf16 [b][z][y][x][c16])
//   c2b     : 75,497,472  (8,388,608 B bf16 [b][z][y][x][c32])
//   featb   : 92,274,688  (2,097,152 B bf16 [b][f], f = oc*512+zo*64+y*8+x)
//   w2b     : 98,566,144  (28,672 B bf16 [28 sh][32 oc][16 c])
//   w3b     : 98,697,216  (110,592 B bf16 [27 sh][64 oc][32 c])
//   fc_wb   : 98,807,808  (8,388,608 B bf16 [l][32768])
// ---------------------------------------------------------------------------

typedef __attribute__((ext_vector_type(8))) short bf16x8;
typedef __attribute__((ext_vector_type(4))) float f32x4;

__device__ inline unsigned short f2bf(float f) {
    __hip_bfloat16 h = __float2bfloat16(f);
    return *reinterpret_cast<unsigned short*>(&h);
}

// Fused: blocks 0..2047 scatter; 2048..2319 w2/w3 transpose; 2320..4367 fc_w->bf16.
__global__ void k_scatter_wtrans(const float* __restrict__ coords,
                                 unsigned char* __restrict__ grid,
                                 const float* __restrict__ w2,
                                 unsigned short* __restrict__ w2b,
                                 const float* __restrict__ w3,
                                 unsigned short* __restrict__ w3b,
                                 const float* __restrict__ fc_w,
                                 unsigned short* __restrict__ fc_wb) {
    int blk = blockIdx.x;
    if (blk < 2048) {
        int i = blk * 256 + threadIdx.x;             // 524288 threads
        float cx = coords[3 * i + 0];
        float cy = coords[3 * i + 1];
        float cz = coords[3 * i + 2];
        int ix = (int)((cx + 1.0f) * 0.5f * 63.0f);
        int iy = (int)((cy + 1.0f) * 0.5f * 63.0f);
        int iz = (int)((cz + 1.0f) * 0.5f * 63.0f);
        ix = min(max(ix, 0), 63);
        iy = min(max(iy, 0), 63);
        iz = min(max(iz, 0), 63);
        int b = i >> 14;
        grid[((b * 64 + iz) * 64 + iy) * 64 + ix] = 1;
    } else if (blk < 2320) {
        int i = (blk - 2048) * 256 + threadIdx.x;    // 0..69631
        if (i < 14336) {
            int sh = i >> 9, oc = (i >> 4) & 31, c = i & 15;
            float v = (sh < 27) ? w2[oc * 432 + c * 27 + sh] : 0.0f;
            w2b[i] = f2bf(v);
        } else {
            int j = i - 14336;
            if (j < 55296) {
                int sh = j >> 11, oc = (j >> 5) & 63, c = j & 31;
                w3b[j] = f2bf(w3[oc * 864 + c * 27 + sh]);
            }
        }
    } else {
        int u = (blk - 2320) * 256 + threadIdx.x;    // 0..524287, 8 elems each
        const float* src = fc_w + (size_t)u * 8;
        float4 lo = *(const float4*)src;
        float4 hi = *(const float4*)(src + 4);
        unsigned int dw[4];
        dw[0] = (unsigned int)f2bf(lo.x) | ((unsigned int)f2bf(lo.y) << 16);
        dw[1] = (unsigned int)f2bf(lo.z) | ((unsigned int)f2bf(lo.w) << 16);
        dw[2] = (unsigned int)f2bf(hi.x) | ((unsigned int)f2bf(hi.y) << 16);
        dw[3] = (unsigned int)f2bf(hi.z) | ((unsigned int)f2bf(hi.w) << 16);
        *(int4*)(fc_wb + (size_t)u * 8) = int4{(int)dw[0], (int)dw[1], (int)dw[2], (int)dw[3]};
    }
}

// conv1 (LDS-staged halo): block = (b, zb, yb, xb) -> outputs (4z, 8y, 8x).
__global__ __launch_bounds__(256) void k_conv1(
        const unsigned char* __restrict__ grid,
        const float* __restrict__ w1,
        const float* __restrict__ b1,
        unsigned short* __restrict__ c1b) {
    __shared__ float hal[9 * 17 * 20];               // 12,240 B
    const int t = threadIdx.x;
    const int blk = blockIdx.x;                      // 4096 blocks
    const int b = blk >> 7;
    const int zb = (blk >> 4) & 7;
    const int yb = (blk >> 2) & 3;
    const int xb = blk & 3;
    const int iz0 = 8 * zb - 1, iy0 = 16 * yb - 1, ix0 = 16 * xb - 1;

    const unsigned char* g = grid + b * 262144;
    for (int i = t; i < 2601; i += 256) {
        int hz = i / 289, rm = i - hz * 289;
        int hy = rm / 17, hx = rm - hy * 17;
        int iz = iz0 + hz, iy = iy0 + hy, ix = ix0 + hx;
        bool ok = (iz >= 0) & (iy >= 0) & (ix >= 0);
        float v = ok ? (float)g[(iz * 64 + iy) * 64 + ix] : 0.0f;
        int ux = (hx & 1) ? 10 + (hx >> 1) : (hx >> 1);
        hal[(hz * 17 + hy) * 20 + ux] = v;
    }
    __syncthreads();

    const int x = t & 7, y = (t >> 3) & 7, tz = t >> 6;
    const int base = (2 * tz * 17) * 20 + (2 * y) * 20 + x;
    float in27[27];
#pragma unroll
    for (int kz = 0; kz < 3; ++kz)
#pragma unroll
        for (int ky = 0; ky < 3; ++ky)
#pragma unroll
            for (int kx = 0; kx < 3; ++kx) {
                int uxo = (kx == 1) ? 10 : ((kx == 2) ? 1 : 0);
                in27[kz * 9 + ky * 3 + kx] =
                    hal[base + (kz * 17 + ky) * 20 + uxo];
            }
    float r[16];
#pragma unroll
    for (int oc = 0; oc < 16; ++oc) {
        float acc = b1[oc];
#pragma unroll
        for (int k = 0; k < 27; ++k) acc = fmaf(w1[oc * 27 + k], in27[k], acc);
        r[oc] = fmaxf(acc, 0.0f);
    }
    unsigned int dw[8];
#pragma unroll
    for (int j = 0; j < 8; ++j)
        dw[j] = (unsigned int)f2bf(r[2 * j]) | ((unsigned int)f2bf(r[2 * j + 1]) << 16);
    int oz = 4 * zb + tz, oy = 8 * yb + y, ox = 8 * xb + x;
    size_t idx = ((size_t)(b * 32 + oz) * 32 + oy) * 32 + ox;
    char* base_o = (char*)c1b + idx * 32;
    *(int4*)base_o        = int4{(int)dw[0], (int)dw[1], (int)dw[2], (int)dw[3]};
    *(int4*)(base_o + 16) = int4{(int)dw[4], (int)dw[5], (int)dw[6], (int)dw[7]};
}

// ---------------------------------------------------------------------------
// conv2 implicit GEMM, x-split: block=(b,zo,xh), M=128, N=32 oc, K=432.
// ---------------------------------------------------------------------------
__device__ constexpr int abase2(int sh) {
    return (sh / 9) * 18480 + (((sh % 9) / 3) & 1) * 9520 +
           (((sh % 9) / 3) >> 1) * 560 + (sh % 3) * 32;
}

__global__ __launch_bounds__(512, 4) void k_conv2_mfma(
        const unsigned short* __restrict__ c1b,
        const unsigned short* __restrict__ w2b,
        const float* __restrict__ b2,
        unsigned short* __restrict__ c2b) {
    __shared__ __align__(16) char smem[55440];
    const int t = threadIdx.x;
    const int b = blockIdx.x >> 5;
    const int zo = (blockIdx.x >> 1) & 15;
    const int xh = blockIdx.x & 1;
    const int lane = t & 63;
    const int wid = t >> 6;

    const char* src = (const char*)c1b + (size_t)b * (32768 * 32);
    for (int i = t; i < 1683; i += 512) {
        int kz = i / 561, rem = i - kz * 561;
        int iy_st = rem / 17, c = rem - iy_st * 17;
        int iz = 2 * zo + kz - 1;
        int iy = iy_st - 1;
        int ix = (xh << 4) + c - 1;
        int4 v0 = {0, 0, 0, 0}, v1 = {0, 0, 0, 0};
        if ((iz >= 0) & (iy >= 0) & (ix >= 0)) {
            const char* gp = src + ((size_t)((iz * 32 + iy) * 32 + ix)) * 32;
            v0 = *(const int4*)gp;
            v1 = *(const int4*)(gp + 16);
        }
        char* d = smem + kz * 18480 + (iy_st & 1) * 9520 + (iy_st >> 1) * 560 + c * 32;
        *(int4*)d = v0;
        *(int4*)(d + 16) = v1;
    }
    __syncthreads();

    const int y16 = lane & 15;
    const int g = lane >> 4;
    const int h = g & 1;
    const int s = g >> 1;
    const int laneA = y16 * 560 + h * 16;
    const int laneB = (lane & 15) * 32 + h * 16 + s * 1024;
    const int xl64 = wid * 64;
    const char* wbase = (const char*)w2b;

    f32x4 acc0 = {0, 0, 0, 0}, acc1 = {0, 0, 0, 0};

#pragma unroll
    for (int sp = 0; sp < 14; ++sp) {
        const int sh0 = 2 * sp;
        const int sh1 = (2 * sp + 1 < 27) ? 2 * sp + 1 : 26;
        const int a0 = abase2(sh0);
        const int d01 = abase2(sh1) - a0;
        bf16x8 A = *(const bf16x8*)(smem + laneA + a0 + (s ? d01 : 0) + xl64);
        const char* wb = wbase + sp * 2048 + laneB;
        bf16x8 B0 = *(const bf16x8*)wb;
        bf16x8 B1 = *(const bf16x8*)(wb + 512);
        acc0 = __builtin_amdgcn_mfma_f32_16x16x32_bf16(A, B0, acc0, 0, 0, 0);
        acc1 = __builtin_amdgcn_mfma_f32_16x16x32_bf16(A, B1, acc1, 0, 0, 0);
    }

    __syncthreads();
    float* sOut = (float*)smem;                      // [32 oc][129]
    {
        int ocl = lane & 15;
        int yb = (lane >> 4) * 4;
#pragma unroll
        for (int r = 0; r < 4; ++r) {
            sOut[ocl * 129        + (yb + r) * 8 + wid] = acc0[r];
            sOut[(ocl + 16) * 129 + (yb + r) * 8 + wid] = acc1[r];
        }
    }
    __syncthreads();
    {
        int vox = t >> 2, q = t & 3;
        unsigned int dw[4];
#pragma unroll
        for (int j = 0; j < 4; ++j) {
            int oc0 = 8 * q + 2 * j;
            float v0 = fmaxf(sOut[oc0 * 129 + vox] + b2[oc0], 0.0f);
            float v1 = fmaxf(sOut[(oc0 + 1) * 129 + vox] + b2[oc0 + 1], 0.0f);
            dw[j] = (unsigned int)f2bf(v0) | ((unsigned int)f2bf(v1) << 16);
        }
        char* dst = (char*)c2b +
                    ((size_t)b * 4096 + zo * 256 + (vox >> 3) * 16 + xh * 8 + (vox & 7)) * 64 +
                    q * 16;
        *(int4*)dst = int4{(int)dw[0], (int)dw[1], (int)dw[2], (int)dw[3]};
    }
}

// ---------------------------------------------------------------------------
// conv3 implicit GEMM (x-parity-split voxels); epilogue -> featb bf16.
// ---------------------------------------------------------------------------
__global__ __launch_bounds__(512) void k_conv3_mfma(
        const unsigned short* __restrict__ c2b,
        const unsigned short* __restrict__ w3b,
        const float* __restrict__ b3,
        unsigned short* __restrict__ featb) {
    __shared__ __align__(16) char smem[55488];
    const int t = threadIdx.x;
    const int b = blockIdx.x >> 3;
    const int zo = blockIdx.x & 7;
    const int lane = t & 63;
    const int wid = t >> 6;

    if (t < 396) {
        int p3 = t / 132, j = t % 132;
        int v = j >> 2, g = j & 3;
        int iy_st = (v < 17) ? 0 : (v - 16);
        int ix_st = (v < 17) ? v : 0;
        int ux = (ix_st & 1) ? 9 + (ix_st >> 1) : (ix_st >> 1);
        int u = (p3 * 17 + iy_st) * 17 + ux;
        *(int4*)(smem + u * 64 + g * 16) = int4{0, 0, 0, 0};
    }

    const char* src = (const char*)c2b + (size_t)b * 262144;
#pragma unroll
    for (int r = 0; r < 6; ++r) {
        int i = r * 512 + t;
        int g = i & 3, vox = i >> 2;
        int kz = vox >> 8, pos = vox & 255;
        int iy = pos >> 4, ix = pos & 15;
        int iz = 2 * zo + kz - 1;
        int4 v = {0, 0, 0, 0};
        if (iz >= 0)
            v = *(const int4*)(src + ((size_t)(iz * 256 + pos)) * 64 + g * 16);
        int ix_st = ix + 1;
        int ux = (ix_st & 1) ? 9 + (ix_st >> 1) : (ix_st >> 1);
        int u = (kz * 17 + iy + 1) * 17 + ux;
        *(int4*)(smem + u * 64 + g * 16) = v;
    }
    __syncthreads();

    const int mt = wid >> 1;
    const int ntp = wid & 1;
    const int m = mt * 16 + (lane & 15);
    const int y = m >> 3, x = m & 7;
    const int g = lane >> 4;
    const int laneA = (34 * y + x) * 64 + g * 16;
    const char* wb_base = (const char*)w3b + (ntp * 32 + (lane & 15)) * 64 + g * 16;

    f32x4 acc0 = {0, 0, 0, 0}, acc1 = {0, 0, 0, 0};

#pragma unroll
    for (int sh = 0; sh < 27; ++sh) {
        const int kz = sh / 9, ky = (sh % 9) / 3, kx = sh % 3;
        const int uxc = (kx == 0) ? 0 : ((kx == 1) ? 9 : 1);
        const int aoff = (289 * kz + 17 * ky + uxc) * 64;
        bf16x8 A = *(const bf16x8*)(smem + laneA + aoff);
        const char* wb = wb_base + sh * 4096;
        bf16x8 B0 = *(const bf16x8*)wb;
        bf16x8 B1 = *(const bf16x8*)(wb + 1024);
        acc0 = __builtin_amdgcn_mfma_f32_16x16x32_bf16(A, B0, acc0, 0, 0, 0);
        acc1 = __builtin_amdgcn_mfma_f32_16x16x32_bf16(A, B1, acc1, 0, 0, 0);
    }

    __syncthreads();
    float* sOut = (float*)smem;                      // [64 oc][65]
    {
        int ocl = lane & 15;
        int mb = mt * 16 + (lane >> 4) * 4;
#pragma unroll
        for (int r = 0; r < 4; ++r) {
            sOut[(ntp * 32 + ocl) * 65 + mb + r]      = acc0[r];
            sOut[(ntp * 32 + 16 + ocl) * 65 + mb + r] = acc1[r];
        }
    }
    __syncthreads();
    {
        int oc = t >> 3, q = t & 7;
        float bb = b3[oc];
        unsigned int dw[4];
#pragma unroll
        for (int j = 0; j < 4; ++j) {
            float v0 = fmaxf(sOut[oc * 65 + q * 8 + 2 * j] + bb, 0.0f);
            float v1 = fmaxf(sOut[oc * 65 + q * 8 + 2 * j + 1] + bb, 0.0f);
            dw[j] = (unsigned int)f2bf(v0) | ((unsigned int)f2bf(v1) << 16);
        }
        char* dst = (char*)featb + (size_t)b * 65536 + oc * 1024 + zo * 128 + q * 16;
        *(int4*)dst = int4{(int)dw[0], (int)dw[1], (int)dw[2], (int)dw[3]};
    }
}

// ---------------------------------------------------------------------------
// FC on MFMA: out(32,128) = featb(32,32768) @ fc_wb^T + fc_b.
// 256 blocks, K=128 each. M=32 b, N=128 l. A staged in LDS (stride 272 B ->
// 2-way-free ds_read_b128); B straight from L2. fp32 atomicAdd epilogue
// (out pre-zeroed); bias added by block 0 only.
// ---------------------------------------------------------------------------
__global__ __launch_bounds__(256) void k_fc_mfma(
        const unsigned short* __restrict__ featb,
        const unsigned short* __restrict__ fc_wb,
        const float* __restrict__ fc_b,
        float* __restrict__ out) {
    __shared__ __align__(16) char smem[32 * 272];    // 8,704 B
    const int t = threadIdx.x;
    const int blk = blockIdx.x;                      // 256
    const int f0 = blk << 7;                         // f-chunk of 128

    {
        int b = t >> 3, seg = t & 7;                 // 32 B per thread
        const char* gp = (const char*)featb + (size_t)b * 65536 + f0 * 2 + seg * 32;
        char* d = smem + b * 272 + seg * 32;
        *(int4*)d = *(const int4*)gp;
        *(int4*)(d + 16) = *(const int4*)(gp + 16);
    }
    __syncthreads();

    const int lane = t & 63;
    const int w = t >> 6;                            // 4 waves -> l-tiles {2w,2w+1}
    const int n = lane & 15;
    const int g = lane >> 4;

    f32x4 acc00 = {0, 0, 0, 0}, acc01 = {0, 0, 0, 0};
    f32x4 acc10 = {0, 0, 0, 0}, acc11 = {0, 0, 0, 0};

    const char* wb0 = (const char*)fc_wb + ((size_t)(2 * w * 16 + n)) * 65536 + f0 * 2 + g * 16;
    const char* wb1 = wb0 + 16 * 65536;

#pragma unroll
    for (int ks = 0; ks < 4; ++ks) {
        bf16x8 A0 = *(const bf16x8*)(smem + n * 272 + ks * 64 + g * 16);
        bf16x8 A1 = *(const bf16x8*)(smem + (16 + n) * 272 + ks * 64 + g * 16);
        bf16x8 B0 = *(const bf16x8*)(wb0 + ks * 64);
        bf16x8 B1 = *(const bf16x8*)(wb1 + ks * 64);
        acc00 = __builtin_amdgcn_mfma_f32_16x16x32_bf16(A0, B0, acc00, 0, 0, 0);
        acc10 = __builtin_amdgcn_mfma_f32_16x16x32_bf16(A1, B0, acc10, 0, 0, 0);
        acc01 = __builtin_amdgcn_mfma_f32_16x16x32_bf16(A0, B1, acc01, 0, 0, 0);
        acc11 = __builtin_amdgcn_mfma_f32_16x16x32_bf16(A1, B1, acc11, 0, 0, 0);
    }

    // D: row=(lane>>4)*4+r -> b; col=lane&15 -> l within tile.
    const int bo = (lane >> 4) * 4;
    const int l0 = 2 * w * 16 + (lane & 15);
    const int l1 = l0 + 16;
    const bool bias = (blk == 0);
    const float bb0 = bias ? fc_b[l0] : 0.0f;
    const float bb1 = bias ? fc_b[l1] : 0.0f;
#pragma unroll
    for (int r = 0; r < 4; ++r) {
        atomicAdd(&out[(bo + r) * 128 + l0],      acc00[r] + bb0);
        atomicAdd(&out[(bo + r + 16) * 128 + l0], acc10[r] + bb0);
        atomicAdd(&out[(bo + r) * 128 + l1],      acc01[r] + bb1);
        atomicAdd(&out[(bo + r + 16) * 128 + l1], acc11[r] + bb1);
    }
}

extern "C" void kernel_launch(void* const* d_in, const int* in_sizes, int n_in,
                              void* d_out, int out_size, void* d_ws, size_t ws_size,
                              hipStream_t stream) {
    const float* coords = (const float*)d_in[0];
    const float* w1 = (const float*)d_in[1];
    const float* b1 = (const float*)d_in[2];
    const float* w2 = (const float*)d_in[3];
    const float* b2 = (const float*)d_in[4];
    const float* w3 = (const float*)d_in[5];
    const float* b3 = (const float*)d_in[6];
    const float* fc_w = (const float*)d_in[7];
    const float* fc_b = (const float*)d_in[8];

    unsigned char* grid_u8 = (unsigned char*)d_ws;
    unsigned short* c1b = (unsigned short*)((char*)d_ws + 8388608);
    unsigned short* c2b = (unsigned short*)((char*)d_ws + 75497472);
    unsigned short* featb = (unsigned short*)((char*)d_ws + 92274688);
    unsigned short* w2b = (unsigned short*)((char*)d_ws + 98566144);
    unsigned short* w3b = (unsigned short*)((char*)d_ws + 98697216);
    unsigned short* fc_wb = (unsigned short*)((char*)d_ws + 98807808);
    float* out = (float*)d_out;

    hipMemsetAsync(grid_u8, 0, 8388608, stream);
    hipMemsetAsync(out, 0, 32 * 128 * sizeof(float), stream);

    k_scatter_wtrans<<<4368, 256, 0, stream>>>(coords, grid_u8, w2, w2b, w3, w3b,
                                               fc_w, fc_wb);
    k_conv1<<<4096, 256, 0, stream>>>(grid_u8, w1, b1, c1b);
    k_conv2_mfma<<<1024, 512, 0, stream>>>(c1b, w2b, b2, c2b);
    k_conv3_mfma<<<256, 512, 0, stream>>>(c2b, w3b, b3, featb);
    k_fc_mfma<<<256, 256, 0, stream>>>(featb, fc_wb, fc_b, out);
}